// Round 7
// baseline (1001.255 us; speedup 1.0000x reference)
//
#include <hip/hip_runtime.h>
#include <hip/hip_bf16.h>
#include <hip/hip_fp16.h>

#define NBU8 65536     // u8-packed bins per pass (64 KB LDS)
#define NB16 32768     // u16-packed bins per pass (64 KB LDS)
#define TPBH 1024

// ---- u8-packed LDS histogram; grid = (chunk_blocks, passes) --------------
// also zeroes maxima (runs before any reduce)
__global__ __launch_bounds__(TPBH) void kh_hist(const int* __restrict__ keys,
                                                unsigned char* __restrict__ part,
                                                unsigned* __restrict__ maxima,
                                                int E, int chunk, int npu) {
    __shared__ unsigned bins[NBU8 / 4];       // 64 KB, 4 u8 counters per word
    int b = blockIdx.x, t = threadIdx.x;
    if (b == 0 && blockIdx.y == 0 && t < 2) maxima[t] = 0u;
    int base = blockIdx.y * NBU8;
    int e0 = b * chunk, e1 = min(E, e0 + chunk);
    for (int j = t; j < NBU8 / 4; j += TPBH) bins[j] = 0u;
    __syncthreads();
    for (int e = e0 + t; e < e1; e += TPBH) {
        int k = keys[e] - base;
        if ((unsigned)k < NBU8) atomicAdd(&bins[k >> 2], 1u << ((k & 3) << 3));
    }
    __syncthreads();
    unsigned* dst = (unsigned*)(part + (size_t)b * npu + base);
    for (int j = t; j < NBU8 / 4; j += TPBH) dst[j] = bins[j];
}

// ---- scan stage 1 (fused u8-partial reduce): cnt + block-local ex-scan ---
__global__ __launch_bounds__(256) void k_scan1(const unsigned char* __restrict__ part,
                                               int nb, int npu,
                                               int* __restrict__ cnt,
                                               int* __restrict__ roff,
                                               int* __restrict__ bsum, int n) {
    __shared__ int s[256];
    int b = blockIdx.x, t = threadIdx.x;
    int i = b * 256 + t;
    int v = 0;
    if (i < n) {
        for (int k = 0; k < nb; ++k) v += part[(size_t)k * npu + i];
        cnt[i] = v;
    }
    s[t] = v;
    __syncthreads();
    for (int off = 1; off < 256; off <<= 1) {
        int x = (t >= off) ? s[t - off] : 0;
        __syncthreads();
        s[t] += x;
        __syncthreads();
    }
    if (i < n) roff[i] = s[t] - v;
    if (t == 255) bsum[b] = s[255];
}

// ---- scan stage 2: exclusive scan of block sums (1 block, nb<=512) -------
__global__ __launch_bounds__(512) void k_scan2(int* __restrict__ bsum, int nb) {
    __shared__ int s[512];
    int t = threadIdx.x;
    int v = (t < nb) ? bsum[t] : 0;
    s[t] = v;
    __syncthreads();
    for (int off = 1; off < 512; off <<= 1) {
        int x = (t >= off) ? s[t - off] : 0;
        __syncthreads();
        s[t] += x;
        __syncthreads();
    }
    if (t < nb) bsum[t] = s[t] - v;
}

// ---- scan stage 3: finalize roff + dis -----------------------------------
__global__ void k_scan3(int* __restrict__ roff, const int* __restrict__ bsum,
                        const int* __restrict__ cnt, float* __restrict__ dis, int n, int E) {
    int i = blockIdx.x * blockDim.x + threadIdx.x;
    if (i < n) {
        roff[i] += bsum[i >> 8];
        dis[i] = rsqrtf((float)cnt[i] + 1.0f);    // +1 self loop
    }
    if (i == 0) roff[n] = E;
}

// ---- per-node exclusive prefix of u8 partials, XCD-grouped block order ---
__global__ void kh_prefix(unsigned char* __restrict__ part, int nb, int npu, int n) {
    int i = blockIdx.x * blockDim.x + threadIdx.x;
    if (i >= n) return;
    int run = 0;
    for (int g = 0; g < 8; ++g) {
        for (int b = g; b < nb; b += 8) {
            size_t idx = (size_t)b * npu + i;
            int v = part[idx];
            part[idx] = (unsigned char)run;
            run += v;
        }
    }
}

// ---- CSR fill via u8-packed LDS cursors; grid = (chunk_blocks, passes) ---
__global__ __launch_bounds__(TPBH) void kh_fill(const int* __restrict__ col,
                                                const int* __restrict__ row,
                                                const int* __restrict__ roff,
                                                const unsigned char* __restrict__ pref,
                                                int* __restrict__ esrc,
                                                int E, int chunk, int npu) {
    __shared__ unsigned curs[NBU8 / 4];       // 64 KB, 4 u8 local counters/word
    int b = blockIdx.x, t = threadIdx.x;
    int base = blockIdx.y * NBU8;
    int e0 = b * chunk, e1 = min(E, e0 + chunk);
    for (int j = t; j < NBU8 / 4; j += TPBH) curs[j] = 0u;
    __syncthreads();
    const unsigned char* pb = pref + (size_t)b * npu;
    for (int e = e0 + t; e < e1; e += TPBH) {
        int c = col[e], r = row[e];
        int cl = c - base;
        if ((unsigned)cl < NBU8) {
            unsigned sh = (cl & 3) << 3;
            unsigned old = atomicAdd(&curs[cl >> 2], 1u << sh);
            unsigned local = (old >> sh) & 0xFFu;
            int slot = roff[c] + (int)pb[c] + (int)local;
            esrc[slot] = r;
        }
    }
}

// ---- u16 integer LDS histogram-accumulate: part[row] += odeg_i[col] ------
__global__ __launch_bounds__(TPBH) void kh_histacc(const int* __restrict__ row,
                                                   const int* __restrict__ col,
                                                   const int* __restrict__ odeg_i,
                                                   unsigned short* __restrict__ part,
                                                   int E, int chunk, int npu) {
    __shared__ unsigned bins[NB16 / 2];       // 64 KB, 2 u16 sums per word
    int b = blockIdx.x, t = threadIdx.x;
    int base = blockIdx.y * NB16;
    int e0 = b * chunk, e1 = min(E, e0 + chunk);
    for (int j = t; j < NB16 / 2; j += TPBH) bins[j] = 0u;
    __syncthreads();
    for (int e = e0 + t; e < e1; e += TPBH) {
        int r = row[e] - base;
        if ((unsigned)r < NB16)
            atomicAdd(&bins[r >> 1], (unsigned)odeg_i[col[e]] << ((r & 1) << 4));
    }
    __syncthreads();
    unsigned* dst = (unsigned*)(part + (size_t)b * npu + base);
    for (int j = t; j < NB16 / 2; j += TPBH) dst[j] = bins[j];
}

// ---- reduce u8 partials -> float odeg + int odeg + dmax ------------------
__global__ void kh_reduce_odeg(const unsigned char* __restrict__ part,
                               float* __restrict__ odeg, int* __restrict__ odeg_i,
                               unsigned* __restrict__ maxima, int nb, int npu, int n) {
    int i = blockIdx.x * blockDim.x + threadIdx.x;
    float od = 0.f;
    if (i < n) {
        int s = 0;
        for (int b = 0; b < nb; ++b) s += part[(size_t)b * npu + i];
        od = (float)s;
        odeg[i] = od;
        odeg_i[i] = s;
    }
    for (int off = 32; off > 0; off >>= 1) od = fmaxf(od, __shfl_down(od, off));
    if ((threadIdx.x & 63) == 0) atomicMax(&maxima[0], __float_as_uint(od));
}

// ---- reduce u16 partials -> infl + imax ----------------------------------
__global__ void kh_reduce_infl(const unsigned short* __restrict__ part,
                               const float* __restrict__ odeg,
                               float* __restrict__ infl, unsigned* __restrict__ maxima,
                               int nb, int npu, int n) {
    int i = blockIdx.x * blockDim.x + threadIdx.x;
    float fin = 0.f;
    if (i < n) {
        int s = 0;
        for (int b = 0; b < nb; ++b) s += part[(size_t)b * npu + i];
        float od = odeg[i];
        fin = (od > 0.f) ? (float)s / od : 0.f;
        infl[i] = fin;
    }
    for (int off = 32; off > 0; off >>= 1) fin = fmaxf(fin, __shfl_down(fin, off));
    if ((threadIdx.x & 63) == 0) atomicMax(&maxima[1], __float_as_uint(fin));
}

// ---- h0 = x@W_in+b_in, then hws0 = (h0@Wg0)*dis (fused, no h0 to global) -
__global__ __launch_bounds__(256) void k_in_proj(const float* __restrict__ x,
                                                 const float* __restrict__ W,
                                                 const float* __restrict__ b,
                                                 const float* __restrict__ Wg0,
                                                 const float* __restrict__ dis,
                                                 __half* __restrict__ hws, int n) {
    __shared__ alignas(16) float Ws[128 * 64];   // 32 KB
    __shared__ alignas(16) float xs[64 * 64];    // 16 KB
    __shared__ alignas(16) float W2[64 * 64];    // 16 KB
    int t = threadIdx.x;
    int r0 = blockIdx.x * 64;
    for (int i = t; i < 128 * 64; i += 256) Ws[i] = W[i];
    for (int i = t; i < 64 * 64; i += 256) W2[i] = Wg0[i];

    int c = t & 63, rg = t >> 6;
    float acc[16];
    float bc = b[c];
#pragma unroll
    for (int i = 0; i < 16; ++i) acc[i] = bc;

    const float4* xs4 = (const float4*)xs;
    for (int half = 0; half < 2; ++half) {
        __syncthreads();
        for (int i = t; i < 64 * 16; i += 256) {
            int rr = i >> 4, k4 = i & 15;
            int r = r0 + rr;
            float4 v = (r < n) ? ((const float4*)x)[(size_t)r * 32 + half * 16 + k4]
                               : make_float4(0.f, 0.f, 0.f, 0.f);
            ((float4*)xs)[i] = v;
        }
        __syncthreads();
        for (int k4 = 0; k4 < 16; ++k4) {
            int kk = half * 64 + k4 * 4;
            float w0 = Ws[(kk + 0) * 64 + c];
            float w1 = Ws[(kk + 1) * 64 + c];
            float w2 = Ws[(kk + 2) * 64 + c];
            float w3 = Ws[(kk + 3) * 64 + c];
#pragma unroll
            for (int i = 0; i < 16; ++i) {
                float4 xv = xs4[(rg * 16 + i) * 16 + k4];
                acc[i] = fmaf(xv.x, w0, fmaf(xv.y, w1, fmaf(xv.z, w2, fmaf(xv.w, w3, acc[i]))));
            }
        }
    }
    // stage h tile into xs, then fused 64x64 mm + dis scale -> fp16
    __syncthreads();
#pragma unroll
    for (int i = 0; i < 16; ++i) xs[(rg * 16 + i) * 64 + c] = acc[i];
    __syncthreads();
#pragma unroll 2
    for (int i = 0; i < 16; ++i) {
        int r = r0 + rg * 16 + i;
        if (r >= n) break;
        float s = 0.f;
#pragma unroll
        for (int k4 = 0; k4 < 16; ++k4) {
            float4 hv = xs4[(rg * 16 + i) * 16 + k4];
            s = fmaf(hv.x, W2[(k4 * 4 + 0) * 64 + c],
                fmaf(hv.y, W2[(k4 * 4 + 1) * 64 + c],
                fmaf(hv.z, W2[(k4 * 4 + 2) * 64 + c],
                fmaf(hv.w, W2[(k4 * 4 + 3) * 64 + c], s))));
        }
        hws[(size_t)r * 64 + c] = __float2half(s * dis[r]);
    }
}

// ---- gather + BN/ReLU (+ optional fused next-layer mm), 1 node/wave ------
template<int FUSE_MM>
__global__ __launch_bounds__(512) void k_gather(const int* __restrict__ roff,
                                                const int* __restrict__ esrc,
                                                const uint2* __restrict__ hws_in,
                                                const float* __restrict__ dis,
                                                const float* __restrict__ bg,
                                                const float* __restrict__ gamma,
                                                const float* __restrict__ beta,
                                                const float* __restrict__ Wg,
                                                __half* __restrict__ hws_out,
                                                float* __restrict__ hout, int n) {
    __shared__ alignas(16) float sW[FUSE_MM ? 64 * 64 : 64];
    int t = threadIdx.x;
    if (FUSE_MM) {
        for (int i = t; i < 64 * 64; i += 512) sW[i] = Wg[i];
        __syncthreads();
    }
    int wid = t >> 6, lane = t & 63;
    int node = blockIdx.x * 8 + wid;
    if (node >= n) return;                       // wave-uniform
    int grp = lane >> 4, fl = lane & 15;

    int beg = roff[node], end = roff[node + 1];
    float a0 = 0.f, a1 = 0.f, a2 = 0.f, a3 = 0.f;
    union { unsigned u; __half2 h2; } cv;
#define ACC(v) { cv.u = (v).x; float2 f_ = __half22float2(cv.h2); a0 += f_.x; a1 += f_.y; \
                 cv.u = (v).y; f_ = __half22float2(cv.h2);        a2 += f_.x; a3 += f_.y; }
    if (grp == 0) { uint2 v = hws_in[(size_t)node * 16 + fl]; ACC(v) }   // self loop
    int e = beg + grp;
    for (; e + 4 < end; e += 8) {
        int r0 = esrc[e], r1 = esrc[e + 4];
        uint2 v0 = hws_in[(size_t)r0 * 16 + fl];
        uint2 v1 = hws_in[(size_t)r1 * 16 + fl];
        ACC(v0) ACC(v1)
    }
    if (e < end) { uint2 v = hws_in[(size_t)esrc[e] * 16 + fl]; ACC(v) }
#undef ACC
    // reduce 4 edge-groups (lanes l, l+16, l+32, l+48 hold same features)
    a0 += __shfl_xor(a0, 16); a1 += __shfl_xor(a1, 16);
    a2 += __shfl_xor(a2, 16); a3 += __shfl_xor(a3, 16);
    a0 += __shfl_xor(a0, 32); a1 += __shfl_xor(a1, 32);
    a2 += __shfl_xor(a2, 32); a3 += __shfl_xor(a3, 32);

    float d = dis[node];
    float inv = rsqrtf(1.0f + 1e-5f);
    float4 g4 = ((const float4*)gamma)[fl];
    float4 b4 = ((const float4*)beta)[fl];
    float4 bg4 = ((const float4*)bg)[fl];
    float4 o;
    o.x = fmaxf(fmaf(a0 * d + bg4.x, g4.x * inv, b4.x), 0.0f);
    o.y = fmaxf(fmaf(a1 * d + bg4.y, g4.y * inv, b4.y), 0.0f);
    o.z = fmaxf(fmaf(a2 * d + bg4.z, g4.z * inv, b4.z), 0.0f);
    o.w = fmaxf(fmaf(a3 * d + bg4.w, g4.w * inv, b4.w), 0.0f);

    if (FUSE_MM) {
        // next-layer hws row: broadcast h row across wave via shfl, 64 FMA/lane
        float s = 0.f;
#pragma unroll
        for (int q = 0; q < 16; ++q) {
            float h0 = __shfl(o.x, q);
            float h1 = __shfl(o.y, q);
            float h2 = __shfl(o.z, q);
            float h3 = __shfl(o.w, q);
            s = fmaf(h0, sW[(q * 4 + 0) * 64 + lane],
                fmaf(h1, sW[(q * 4 + 1) * 64 + lane],
                fmaf(h2, sW[(q * 4 + 2) * 64 + lane],
                fmaf(h3, sW[(q * 4 + 3) * 64 + lane], s))));
        }
        hws_out[(size_t)node * 64 + lane] = __float2half(s * d);
    } else {
        if (grp == 0) ((float4*)hout)[(size_t)node * 16 + fl] = o;
    }
}

// -------- fused structural MLP + output head (one node per thread) --------
__global__ __launch_bounds__(256) void k_final(const float* __restrict__ h,
                                               const float* __restrict__ odeg,
                                               const float* __restrict__ infl,
                                               const unsigned* __restrict__ maxima,
                                               const float* __restrict__ Ws1, const float* __restrict__ bs1,
                                               const float* __restrict__ Ws2, const float* __restrict__ bs2,
                                               const float* __restrict__ Wo1, const float* __restrict__ bo1,
                                               const float* __restrict__ Wo2, const float* __restrict__ bo2,
                                               const float* __restrict__ Wo3, const float* __restrict__ bo3,
                                               float* __restrict__ out, int n) {
    __shared__ alignas(16) float sWs1[96], sbs1[32], sWs2T[64 * 32], sbs2[64];
    __shared__ alignas(16) float sWo1[128 * 64], sbo1[64], sWo2[64 * 32], sbo2[32], sWo3[32];
    int t = threadIdx.x;
    for (int i = t; i < 96; i += 256) sWs1[i] = Ws1[i];
    for (int i = t; i < 2048; i += 256) {            // transpose W_s2: [32][64] -> [64][32]
        int j = i >> 6, k = i & 63;
        sWs2T[k * 32 + j] = Ws2[i];
    }
    for (int i = t; i < 8192; i += 256) sWo1[i] = Wo1[i];
    for (int i = t; i < 2048; i += 256) sWo2[i] = Wo2[i];
    if (t < 32) { sbs1[t] = bs1[t]; sbo2[t] = bo2[t]; sWo3[t] = Wo3[t]; }
    if (t < 64) { sbs2[t] = bs2[t]; sbo1[t] = bo1[t]; }
    __syncthreads();

    int i = blockIdx.x * 256 + t;
    if (i >= n) return;

    float dmax = __uint_as_float(maxima[0]);
    float imax = __uint_as_float(maxima[1]);
    float od = odeg[i];
    float sf0 = (dmax > 0.0f) ? od / dmax : od;
    float fin = infl[i];
    float sf2 = (imax > 0.0f) ? fin / imax : fin;

    float hid[32];
#pragma unroll
    for (int j = 0; j < 32; ++j)
        hid[j] = fmaxf(fmaf(sf0, sWs1[j], fmaf(sf2, sWs1[64 + j], sbs1[j])), 0.0f);

    float o1[64];
    const float4* sbo1_4 = (const float4*)sbo1;
#pragma unroll
    for (int c4 = 0; c4 < 16; ++c4) {
        float4 v = sbo1_4[c4];
        o1[c4 * 4] = v.x; o1[c4 * 4 + 1] = v.y; o1[c4 * 4 + 2] = v.z; o1[c4 * 4 + 3] = v.w;
    }

    const float4* sWo1_4 = (const float4*)sWo1;
    const float4* hrow = (const float4*)(h + (size_t)i * 64);
    for (int k4 = 0; k4 < 16; ++k4) {
        float4 hv = hrow[k4];
        float hv_[4] = {hv.x, hv.y, hv.z, hv.w};
#pragma unroll
        for (int j = 0; j < 4; ++j) {
            float hk = hv_[j];
            int k = k4 * 4 + j;
#pragma unroll
            for (int c4 = 0; c4 < 16; ++c4) {
                float4 w = sWo1_4[k * 16 + c4];
                o1[c4 * 4]     = fmaf(hk, w.x, o1[c4 * 4]);
                o1[c4 * 4 + 1] = fmaf(hk, w.y, o1[c4 * 4 + 1]);
                o1[c4 * 4 + 2] = fmaf(hk, w.z, o1[c4 * 4 + 2]);
                o1[c4 * 4 + 3] = fmaf(hk, w.w, o1[c4 * 4 + 3]);
            }
        }
    }
    const float4* sWs2T_4 = (const float4*)sWs2T;
    for (int k = 0; k < 64; ++k) {
        float sek = sbs2[k];
#pragma unroll
        for (int j4 = 0; j4 < 8; ++j4) {
            float4 w = sWs2T_4[k * 8 + j4];
            sek = fmaf(hid[j4 * 4], w.x, fmaf(hid[j4 * 4 + 1], w.y,
                  fmaf(hid[j4 * 4 + 2], w.z, fmaf(hid[j4 * 4 + 3], w.w, sek))));
        }
#pragma unroll
        for (int c4 = 0; c4 < 16; ++c4) {
            float4 w = sWo1_4[(64 + k) * 16 + c4];
            o1[c4 * 4]     = fmaf(sek, w.x, o1[c4 * 4]);
            o1[c4 * 4 + 1] = fmaf(sek, w.y, o1[c4 * 4 + 1]);
            o1[c4 * 4 + 2] = fmaf(sek, w.z, o1[c4 * 4 + 2]);
            o1[c4 * 4 + 3] = fmaf(sek, w.w, o1[c4 * 4 + 3]);
        }
    }

    float o2[32];
    const float4* sbo2_4 = (const float4*)sbo2;
#pragma unroll
    for (int c4 = 0; c4 < 8; ++c4) {
        float4 v = sbo2_4[c4];
        o2[c4 * 4] = v.x; o2[c4 * 4 + 1] = v.y; o2[c4 * 4 + 2] = v.z; o2[c4 * 4 + 3] = v.w;
    }
    const float4* sWo2_4 = (const float4*)sWo2;
#pragma unroll
    for (int c = 0; c < 64; ++c) {
        float v = fmaxf(o1[c], 0.0f);
#pragma unroll
        for (int c4 = 0; c4 < 8; ++c4) {
            float4 w = sWo2_4[c * 8 + c4];
            o2[c4 * 4]     = fmaf(v, w.x, o2[c4 * 4]);
            o2[c4 * 4 + 1] = fmaf(v, w.y, o2[c4 * 4 + 1]);
            o2[c4 * 4 + 2] = fmaf(v, w.z, o2[c4 * 4 + 2]);
            o2[c4 * 4 + 3] = fmaf(v, w.w, o2[c4 * 4 + 3]);
        }
    }

    float o3 = bo3[0];
#pragma unroll
    for (int c2 = 0; c2 < 32; ++c2)
        o3 = fmaf(fmaxf(o2[c2], 0.0f), sWo3[c2], o3);

    out[i] = 1.0f / (1.0f + __expf(-o3));
}

// ==========================================================================
extern "C" void kernel_launch(void* const* d_in, const int* in_sizes, int n_in,
                              void* d_out, int out_size, void* d_ws, size_t ws_size,
                              hipStream_t stream) {
    const float* x     = (const float*)d_in[0];
    const int*   ei    = (const int*)d_in[1];
    const float* W_in  = (const float*)d_in[2];
    const float* b_in  = (const float*)d_in[3];
    const float* W_gcn = (const float*)d_in[4];
    const float* b_gcn = (const float*)d_in[5];
    const float* gamma = (const float*)d_in[6];
    const float* beta  = (const float*)d_in[7];
    const float* Ws1   = (const float*)d_in[8];
    const float* bs1   = (const float*)d_in[9];
    const float* Ws2   = (const float*)d_in[10];
    const float* bs2   = (const float*)d_in[11];
    const float* Wo1   = (const float*)d_in[12];
    const float* bo1   = (const float*)d_in[13];
    const float* Wo2   = (const float*)d_in[14];
    const float* bo2   = (const float*)d_in[15];
    const float* Wo3   = (const float*)d_in[16];
    const float* bo3   = (const float*)d_in[17];
    float* out = (float*)d_out;

    int n = in_sizes[0] / 128;
    int E = in_sizes[1] / 2;
    const int* row = ei;
    const int* col = ei + E;

    int npass8  = (n + NBU8 - 1) / NBU8;     // 2 @ n=100K
    int npass16 = (n + NB16 - 1) / NB16;     // 4 @ n=100K
    size_t NPU8  = (size_t)npass8 * NBU8;    // 131072
    size_t NPU16 = (size_t)npass16 * NB16;   // 131072

    auto al = [](size_t v) { return (v + 255) & ~(size_t)255; };
    size_t fixed = al((NPU8 + 256) * 4)          // roff
                 + al(NPU8 * 4)                  // cnt
                 + al(1024 * 4)                  // bsum
                 + 3 * al(NPU8 * 4)              // dis, odeg, infl
                 + al(NPU8 * 4)                  // odeg_i
                 + al(256)                       // maxima
                 + al((size_t)E * 4)             // esrc
                 + al((size_t)n * 64 * 4)        // h (f32)
                 + 2 * al((size_t)n * 64 * 2);   // hwsA, hwsB (f16)
    int NB = 256;                                // u8 kernels (hist/fill)
    auto partBytes = [&](int nb) {
        size_t a = (size_t)nb * NPU8;            // u8 partials
        size_t b2 = (size_t)(nb / 2) * NPU16 * 2; // u16 partials (NB/2 blocks)
        return a > b2 ? a : b2;
    };
    while (NB > 32 && fixed + partBytes(NB) > ws_size) NB >>= 1;
    int NBa = NB / 2;                            // histacc blocks
    int chunk  = (E + NB - 1) / NB;
    int chunkA = (E + NBa - 1) / NBa;

    char* p = (char*)d_ws;
    unsigned char*  part8  = (unsigned char*)p;     // [NB][NPU8] u8
    unsigned short* part16 = (unsigned short*)p;    // [NBa][NPU16] u16 (later phase)
    p += al(partBytes(NB));
    int* roff = (int*)p;        p += al((NPU8 + 256) * 4);
    int* cnt  = (int*)p;        p += al(NPU8 * 4);
    int* bsum = (int*)p;        p += al(1024 * 4);
    float* dis  = (float*)p;    p += al(NPU8 * 4);
    float* odeg = (float*)p;    p += al(NPU8 * 4);
    float* infl = (float*)p;    p += al(NPU8 * 4);
    int* odeg_i = (int*)p;      p += al(NPU8 * 4);
    unsigned* maxima = (unsigned*)p; p += al(256);
    int* esrc = (int*)p;        p += al((size_t)E * 4);
    float* h   = (float*)p;     p += al((size_t)n * 64 * 4);
    __half* hwsA = (__half*)p;  p += al((size_t)n * 64 * 2);
    __half* hwsB = (__half*)p;

    int gn = (n + 255) / 256;                // <=512 for scan2

    // ---- col-CSR build (no global atomics) ----
    kh_hist<<<dim3(NB, npass8), TPBH, 0, stream>>>(col, part8, maxima, E, chunk, (int)NPU8);
    k_scan1<<<gn, 256, 0, stream>>>(part8, NB, (int)NPU8, cnt, roff, bsum, n);
    k_scan2<<<1, 512, 0, stream>>>(bsum, gn);
    k_scan3<<<gn, 256, 0, stream>>>(roff, bsum, cnt, dis, n, E);
    kh_prefix<<<gn, 256, 0, stream>>>(part8, NB, (int)NPU8, n);
    kh_fill<<<dim3(NB, npass8), TPBH, 0, stream>>>(col, row, roff, part8, esrc, E, chunk, (int)NPU8);

    // ---- structural stats ----
    kh_hist<<<dim3(NB, npass8), TPBH, 0, stream>>>(row, part8, maxima, E, chunk, (int)NPU8);
    kh_reduce_odeg<<<gn, 256, 0, stream>>>(part8, odeg, odeg_i, maxima, NB, (int)NPU8, n);
    kh_histacc<<<dim3(NBa, npass16), TPBH, 0, stream>>>(row, col, odeg_i, part16, E, chunkA, (int)NPU16);
    kh_reduce_infl<<<gn, 256, 0, stream>>>(part16, odeg, infl, maxima, NBa, (int)NPU16, n);

    // ---- GNN (mm fused into producers; h only materialized for k_final) ----
    k_in_proj<<<(n + 63) / 64, 256, 0, stream>>>(x, W_in, b_in, W_gcn, dis, hwsA, n);

    int gg = (n + 7) / 8;
    k_gather<1><<<gg, 512, 0, stream>>>(roff, esrc, (const uint2*)hwsA, dis,
                                        b_gcn + 0 * 64, gamma + 0 * 64, beta + 0 * 64,
                                        W_gcn + (size_t)1 * 64 * 64, hwsB, nullptr, n);
    k_gather<1><<<gg, 512, 0, stream>>>(roff, esrc, (const uint2*)hwsB, dis,
                                        b_gcn + 1 * 64, gamma + 1 * 64, beta + 1 * 64,
                                        W_gcn + (size_t)2 * 64 * 64, hwsA, nullptr, n);
    k_gather<0><<<gg, 512, 0, stream>>>(roff, esrc, (const uint2*)hwsA, dis,
                                        b_gcn + 2 * 64, gamma + 2 * 64, beta + 2 * 64,
                                        nullptr, nullptr, h, n);

    k_final<<<gn, 256, 0, stream>>>(h, odeg, infl, maxima,
                                    Ws1, bs1, Ws2, bs2, Wo1, bo1, Wo2, bo2, Wo3, bo3,
                                    out, n);
}

// Round 8
// 863.835 us; speedup vs baseline: 1.1591x; 1.1591x over previous
//
#include <hip/hip_runtime.h>
#include <hip/hip_bf16.h>
#include <hip/hip_fp16.h>

#define NBU8 65536     // u8-packed bins per pass (64 KB LDS)
#define NB16 32768     // u16-packed bins per pass (64 KB LDS)
#define TPBH 1024

// ---- u8-packed LDS histogram; grid = (chunk_blocks, passes) --------------
// also zeroes maxima (runs before any reduce)
__global__ __launch_bounds__(TPBH) void kh_hist(const int* __restrict__ keys,
                                                unsigned char* __restrict__ part,
                                                unsigned* __restrict__ maxima,
                                                int E, int chunk, int npu) {
    __shared__ unsigned bins[NBU8 / 4];       // 64 KB, 4 u8 counters per word
    int b = blockIdx.x, t = threadIdx.x;
    if (b == 0 && blockIdx.y == 0 && t < 2) maxima[t] = 0u;
    int base = blockIdx.y * NBU8;
    int e0 = b * chunk, e1 = min(E, e0 + chunk);
    for (int j = t; j < NBU8 / 4; j += TPBH) bins[j] = 0u;
    __syncthreads();
    for (int e = e0 + t; e < e1; e += TPBH) {
        int k = keys[e] - base;
        if ((unsigned)k < NBU8) atomicAdd(&bins[k >> 2], 1u << ((k & 3) << 3));
    }
    __syncthreads();
    unsigned* dst = (unsigned*)(part + (size_t)b * npu + base);
    for (int j = t; j < NBU8 / 4; j += TPBH) dst[j] = bins[j];
}

// ---- scan stage 1 (fused u8-partial reduce): cnt + block-local ex-scan ---
__global__ __launch_bounds__(256) void k_scan1(const unsigned char* __restrict__ part,
                                               int nb, int npu,
                                               int* __restrict__ cnt,
                                               int* __restrict__ roff,
                                               int* __restrict__ bsum, int n) {
    __shared__ int s[256];
    int b = blockIdx.x, t = threadIdx.x;
    int i = b * 256 + t;
    int v = 0;
    if (i < n) {
        for (int k = 0; k < nb; ++k) v += part[(size_t)k * npu + i];
        cnt[i] = v;
    }
    s[t] = v;
    __syncthreads();
    for (int off = 1; off < 256; off <<= 1) {
        int x = (t >= off) ? s[t - off] : 0;
        __syncthreads();
        s[t] += x;
        __syncthreads();
    }
    if (i < n) roff[i] = s[t] - v;
    if (t == 255) bsum[b] = s[255];
}

// ---- scan stage 2: exclusive scan of block sums (1 block, nb<=512) -------
__global__ __launch_bounds__(512) void k_scan2(int* __restrict__ bsum, int nb) {
    __shared__ int s[512];
    int t = threadIdx.x;
    int v = (t < nb) ? bsum[t] : 0;
    s[t] = v;
    __syncthreads();
    for (int off = 1; off < 512; off <<= 1) {
        int x = (t >= off) ? s[t - off] : 0;
        __syncthreads();
        s[t] += x;
        __syncthreads();
    }
    if (t < nb) bsum[t] = s[t] - v;
}

// ---- prefix of u8 partials (XCD-grouped) + roff finalize + dis -----------
__global__ void kh_prefix(unsigned char* __restrict__ part, int nb, int npu, int n,
                          int* __restrict__ roff, const int* __restrict__ bsum,
                          const int* __restrict__ cnt, float* __restrict__ dis, int E) {
    int i = blockIdx.x * blockDim.x + threadIdx.x;
    if (i == 0) roff[n] = E;
    if (i >= n) return;
    roff[i] += bsum[i >> 8];
    dis[i] = rsqrtf((float)cnt[i] + 1.0f);       // +1 self loop
    int run = 0;
    for (int g = 0; g < 8; ++g) {
        for (int b = g; b < nb; b += 8) {
            size_t idx = (size_t)b * npu + i;
            int v = part[idx];
            part[idx] = (unsigned char)run;
            run += v;
        }
    }
}

// ---- CSR fill via u8-packed LDS cursors; grid = (chunk_blocks, passes) ---
__global__ __launch_bounds__(TPBH) void kh_fill(const int* __restrict__ col,
                                                const int* __restrict__ row,
                                                const int* __restrict__ roff,
                                                const unsigned char* __restrict__ pref,
                                                int* __restrict__ esrc,
                                                int E, int chunk, int npu) {
    __shared__ unsigned curs[NBU8 / 4];       // 64 KB, 4 u8 local counters/word
    int b = blockIdx.x, t = threadIdx.x;
    int base = blockIdx.y * NBU8;
    int e0 = b * chunk, e1 = min(E, e0 + chunk);
    for (int j = t; j < NBU8 / 4; j += TPBH) curs[j] = 0u;
    __syncthreads();
    const unsigned char* pb = pref + (size_t)b * npu;
    for (int e = e0 + t; e < e1; e += TPBH) {
        int c = col[e], r = row[e];
        int cl = c - base;
        if ((unsigned)cl < NBU8) {
            unsigned sh = (cl & 3) << 3;
            unsigned old = atomicAdd(&curs[cl >> 2], 1u << sh);
            unsigned local = (old >> sh) & 0xFFu;
            int slot = roff[c] + (int)pb[c] + (int)local;
            esrc[slot] = r;
        }
    }
}

// ---- u16 integer LDS histogram-accumulate: part[row] += odeg_i[col] ------
__global__ __launch_bounds__(TPBH) void kh_histacc(const int* __restrict__ row,
                                                   const int* __restrict__ col,
                                                   const int* __restrict__ odeg_i,
                                                   unsigned short* __restrict__ part,
                                                   int E, int chunk, int npu) {
    __shared__ unsigned bins[NB16 / 2];       // 64 KB, 2 u16 sums per word
    int b = blockIdx.x, t = threadIdx.x;
    int base = blockIdx.y * NB16;
    int e0 = b * chunk, e1 = min(E, e0 + chunk);
    for (int j = t; j < NB16 / 2; j += TPBH) bins[j] = 0u;
    __syncthreads();
    for (int e = e0 + t; e < e1; e += TPBH) {
        int r = row[e] - base;
        if ((unsigned)r < NB16)
            atomicAdd(&bins[r >> 1], (unsigned)odeg_i[col[e]] << ((r & 1) << 4));
    }
    __syncthreads();
    unsigned* dst = (unsigned*)(part + (size_t)b * npu + base);
    for (int j = t; j < NB16 / 2; j += TPBH) dst[j] = bins[j];
}

// ---- reduce u8 partials -> float odeg + int odeg + dmax ------------------
__global__ void kh_reduce_odeg(const unsigned char* __restrict__ part,
                               float* __restrict__ odeg, int* __restrict__ odeg_i,
                               unsigned* __restrict__ maxima, int nb, int npu, int n) {
    int i = blockIdx.x * blockDim.x + threadIdx.x;
    float od = 0.f;
    if (i < n) {
        int s = 0;
        for (int b = 0; b < nb; ++b) s += part[(size_t)b * npu + i];
        od = (float)s;
        odeg[i] = od;
        odeg_i[i] = s;
    }
    for (int off = 32; off > 0; off >>= 1) od = fmaxf(od, __shfl_down(od, off));
    if ((threadIdx.x & 63) == 0) atomicMax(&maxima[0], __float_as_uint(od));
}

// ---- reduce u16 partials -> infl + imax ----------------------------------
__global__ void kh_reduce_infl(const unsigned short* __restrict__ part,
                               const float* __restrict__ odeg,
                               float* __restrict__ infl, unsigned* __restrict__ maxima,
                               int nb, int npu, int n) {
    int i = blockIdx.x * blockDim.x + threadIdx.x;
    float fin = 0.f;
    if (i < n) {
        int s = 0;
        for (int b = 0; b < nb; ++b) s += part[(size_t)b * npu + i];
        float od = odeg[i];
        fin = (od > 0.f) ? (float)s / od : 0.f;
        infl[i] = fin;
    }
    for (int off = 32; off > 0; off >>= 1) fin = fmaxf(fin, __shfl_down(fin, off));
    if ((threadIdx.x & 63) == 0) atomicMax(&maxima[1], __float_as_uint(fin));
}

// ---- h0 = x@W_in+b_in, then hws0 = (h0@Wg0)*dis (fused, no h0 to global) -
__global__ __launch_bounds__(256) void k_in_proj(const float* __restrict__ x,
                                                 const float* __restrict__ W,
                                                 const float* __restrict__ b,
                                                 const float* __restrict__ Wg0,
                                                 const float* __restrict__ dis,
                                                 __half* __restrict__ hws, int n) {
    __shared__ alignas(16) float Ws[128 * 64];   // 32 KB
    __shared__ alignas(16) float xs[64 * 64];    // 16 KB
    __shared__ alignas(16) float W2[64 * 64];    // 16 KB
    int t = threadIdx.x;
    int r0 = blockIdx.x * 64;
    for (int i = t; i < 128 * 64; i += 256) Ws[i] = W[i];
    for (int i = t; i < 64 * 64; i += 256) W2[i] = Wg0[i];

    int c = t & 63, rg = t >> 6;
    float acc[16];
    float bc = b[c];
#pragma unroll
    for (int i = 0; i < 16; ++i) acc[i] = bc;

    const float4* xs4 = (const float4*)xs;
    for (int half = 0; half < 2; ++half) {
        __syncthreads();
        for (int i = t; i < 64 * 16; i += 256) {
            int rr = i >> 4, k4 = i & 15;
            int r = r0 + rr;
            float4 v = (r < n) ? ((const float4*)x)[(size_t)r * 32 + half * 16 + k4]
                               : make_float4(0.f, 0.f, 0.f, 0.f);
            ((float4*)xs)[i] = v;
        }
        __syncthreads();
        for (int k4 = 0; k4 < 16; ++k4) {
            int kk = half * 64 + k4 * 4;
            float w0 = Ws[(kk + 0) * 64 + c];
            float w1 = Ws[(kk + 1) * 64 + c];
            float w2 = Ws[(kk + 2) * 64 + c];
            float w3 = Ws[(kk + 3) * 64 + c];
#pragma unroll
            for (int i = 0; i < 16; ++i) {
                float4 xv = xs4[(rg * 16 + i) * 16 + k4];
                acc[i] = fmaf(xv.x, w0, fmaf(xv.y, w1, fmaf(xv.z, w2, fmaf(xv.w, w3, acc[i]))));
            }
        }
    }
    __syncthreads();
#pragma unroll
    for (int i = 0; i < 16; ++i) xs[(rg * 16 + i) * 64 + c] = acc[i];
    __syncthreads();
#pragma unroll 2
    for (int i = 0; i < 16; ++i) {
        int r = r0 + rg * 16 + i;
        if (r >= n) break;
        float s = 0.f;
#pragma unroll
        for (int k4 = 0; k4 < 16; ++k4) {
            float4 hv = xs4[(rg * 16 + i) * 16 + k4];
            s = fmaf(hv.x, W2[(k4 * 4 + 0) * 64 + c],
                fmaf(hv.y, W2[(k4 * 4 + 1) * 64 + c],
                fmaf(hv.z, W2[(k4 * 4 + 2) * 64 + c],
                fmaf(hv.w, W2[(k4 * 4 + 3) * 64 + c], s))));
        }
        hws[(size_t)r * 64 + c] = __float2half(s * dis[r]);
    }
}

// -------- hw = h @ W_gcn; hws(half2) = hw * dis[r] ------------------------
__global__ __launch_bounds__(256) void k_gcn_mm(const float* __restrict__ h,
                                                const float* __restrict__ Wg,
                                                const float* __restrict__ dis,
                                                unsigned* __restrict__ hws, int n) {
    __shared__ alignas(16) float Ws[64 * 64];
    __shared__ alignas(16) float xs[64 * 64];
    int t = threadIdx.x;
    int r0 = blockIdx.x * 64;
    for (int i = t; i < 64 * 64; i += 256) Ws[i] = Wg[i];
    for (int i = t; i < 64 * 16; i += 256) {
        int rr = i >> 4, k4 = i & 15;
        int r = r0 + rr;
        float4 v = (r < n) ? ((const float4*)h)[(size_t)r * 16 + k4]
                           : make_float4(0.f, 0.f, 0.f, 0.f);
        ((float4*)xs)[i] = v;
    }
    __syncthreads();
    int c2 = (t & 31) << 1, rg = t >> 5;     // 2 features x (8 row-groups x 8 rows)
    const float4* xs4 = (const float4*)xs;
    float a0[8], a1[8];
#pragma unroll
    for (int i = 0; i < 8; ++i) { a0[i] = 0.f; a1[i] = 0.f; }
    for (int k4 = 0; k4 < 16; ++k4) {
        float wA0 = Ws[(k4 * 4 + 0) * 64 + c2],     wB0 = Ws[(k4 * 4 + 0) * 64 + c2 + 1];
        float wA1 = Ws[(k4 * 4 + 1) * 64 + c2],     wB1 = Ws[(k4 * 4 + 1) * 64 + c2 + 1];
        float wA2 = Ws[(k4 * 4 + 2) * 64 + c2],     wB2 = Ws[(k4 * 4 + 2) * 64 + c2 + 1];
        float wA3 = Ws[(k4 * 4 + 3) * 64 + c2],     wB3 = Ws[(k4 * 4 + 3) * 64 + c2 + 1];
#pragma unroll
        for (int i = 0; i < 8; ++i) {
            float4 xv = xs4[(rg * 8 + i) * 16 + k4];
            a0[i] = fmaf(xv.x, wA0, fmaf(xv.y, wA1, fmaf(xv.z, wA2, fmaf(xv.w, wA3, a0[i]))));
            a1[i] = fmaf(xv.x, wB0, fmaf(xv.y, wB1, fmaf(xv.z, wB2, fmaf(xv.w, wB3, a1[i]))));
        }
    }
#pragma unroll
    for (int i = 0; i < 8; ++i) {
        int r = r0 + rg * 8 + i;
        if (r < n) {
            float d = dis[r];
            __half2 hv = __floats2half2_rn(a0[i] * d, a1[i] * d);
            hws[(size_t)r * 32 + (t & 31)] = *(unsigned*)&hv;
        }
    }
}

// -------- gather + BN/bias/ReLU: 8 lanes/node, uint4 (8 feats) per lane ---
__global__ __launch_bounds__(256) void k_gather(const int* __restrict__ roff,
                                                const int* __restrict__ esrc,
                                                const uint4* __restrict__ hws,
                                                const float* __restrict__ dis,
                                                const float* __restrict__ bg,
                                                const float* __restrict__ gamma,
                                                const float* __restrict__ beta,
                                                float* __restrict__ h, int n) {
    int t = threadIdx.x;
    int node = blockIdx.x * 32 + (t >> 3);
    int ln = t & 7;                           // uint4 index within row (8 feats)
    if (node >= n) return;

    int beg = roff[node], end = roff[node + 1];
    float a[8];
#pragma unroll
    for (int j = 0; j < 8; ++j) a[j] = 0.f;
    union { unsigned u; __half2 h2; } cv;
#define ACC(v) { cv.u = (v).x; float2 f_ = __half22float2(cv.h2); a[0] += f_.x; a[1] += f_.y; \
                 cv.u = (v).y; f_ = __half22float2(cv.h2);        a[2] += f_.x; a[3] += f_.y; \
                 cv.u = (v).z; f_ = __half22float2(cv.h2);        a[4] += f_.x; a[5] += f_.y; \
                 cv.u = (v).w; f_ = __half22float2(cv.h2);        a[6] += f_.x; a[7] += f_.y; }
    {
        uint4 v = hws[(size_t)node * 8 + ln];   // self-loop term
        ACC(v)
    }
    int e = beg;
    for (; e + 4 <= end; e += 4) {
        int r0 = esrc[e], r1 = esrc[e + 1], r2 = esrc[e + 2], r3 = esrc[e + 3];
        uint4 v0 = hws[(size_t)r0 * 8 + ln];
        uint4 v1 = hws[(size_t)r1 * 8 + ln];
        uint4 v2 = hws[(size_t)r2 * 8 + ln];
        uint4 v3 = hws[(size_t)r3 * 8 + ln];
        ACC(v0) ACC(v1) ACC(v2) ACC(v3)
    }
    for (; e < end; ++e) {
        uint4 v = hws[(size_t)esrc[e] * 8 + ln];
        ACC(v)
    }
#undef ACC
    float d = dis[node];
    float inv = rsqrtf(1.0f + 1e-5f);
    float4 g0 = ((const float4*)gamma)[ln * 2], g1 = ((const float4*)gamma)[ln * 2 + 1];
    float4 b0 = ((const float4*)beta)[ln * 2],  b1 = ((const float4*)beta)[ln * 2 + 1];
    float4 q0 = ((const float4*)bg)[ln * 2],    q1 = ((const float4*)bg)[ln * 2 + 1];
    float4 o0, o1;
    o0.x = fmaxf(fmaf(a[0] * d + q0.x, g0.x * inv, b0.x), 0.0f);
    o0.y = fmaxf(fmaf(a[1] * d + q0.y, g0.y * inv, b0.y), 0.0f);
    o0.z = fmaxf(fmaf(a[2] * d + q0.z, g0.z * inv, b0.z), 0.0f);
    o0.w = fmaxf(fmaf(a[3] * d + q0.w, g0.w * inv, b0.w), 0.0f);
    o1.x = fmaxf(fmaf(a[4] * d + q1.x, g1.x * inv, b1.x), 0.0f);
    o1.y = fmaxf(fmaf(a[5] * d + q1.y, g1.y * inv, b1.y), 0.0f);
    o1.z = fmaxf(fmaf(a[6] * d + q1.z, g1.z * inv, b1.z), 0.0f);
    o1.w = fmaxf(fmaf(a[7] * d + q1.w, g1.w * inv, b1.w), 0.0f);
    ((float4*)h)[(size_t)node * 16 + ln * 2]     = o0;
    ((float4*)h)[(size_t)node * 16 + ln * 2 + 1] = o1;
}

// -------- fused structural MLP + output head (one node per thread) --------
__global__ __launch_bounds__(256) void k_final(const float* __restrict__ h,
                                               const float* __restrict__ odeg,
                                               const float* __restrict__ infl,
                                               const unsigned* __restrict__ maxima,
                                               const float* __restrict__ Ws1, const float* __restrict__ bs1,
                                               const float* __restrict__ Ws2, const float* __restrict__ bs2,
                                               const float* __restrict__ Wo1, const float* __restrict__ bo1,
                                               const float* __restrict__ Wo2, const float* __restrict__ bo2,
                                               const float* __restrict__ Wo3, const float* __restrict__ bo3,
                                               float* __restrict__ out, int n) {
    __shared__ alignas(16) float sWs1[96], sbs1[32], sWs2T[64 * 32], sbs2[64];
    __shared__ alignas(16) float sWo1[128 * 64], sbo1[64], sWo2[64 * 32], sbo2[32], sWo3[32];
    int t = threadIdx.x;
    for (int i = t; i < 96; i += 256) sWs1[i] = Ws1[i];
    for (int i = t; i < 2048; i += 256) {            // transpose W_s2: [32][64] -> [64][32]
        int j = i >> 6, k = i & 63;
        sWs2T[k * 32 + j] = Ws2[i];
    }
    for (int i = t; i < 8192; i += 256) sWo1[i] = Wo1[i];
    for (int i = t; i < 2048; i += 256) sWo2[i] = Wo2[i];
    if (t < 32) { sbs1[t] = bs1[t]; sbo2[t] = bo2[t]; sWo3[t] = Wo3[t]; }
    if (t < 64) { sbs2[t] = bs2[t]; sbo1[t] = bo1[t]; }
    __syncthreads();

    int i = blockIdx.x * 256 + t;
    if (i >= n) return;

    float dmax = __uint_as_float(maxima[0]);
    float imax = __uint_as_float(maxima[1]);
    float od = odeg[i];
    float sf0 = (dmax > 0.0f) ? od / dmax : od;
    float fin = infl[i];
    float sf2 = (imax > 0.0f) ? fin / imax : fin;

    float hid[32];
#pragma unroll
    for (int j = 0; j < 32; ++j)
        hid[j] = fmaxf(fmaf(sf0, sWs1[j], fmaf(sf2, sWs1[64 + j], sbs1[j])), 0.0f);

    float o1[64];
    const float4* sbo1_4 = (const float4*)sbo1;
#pragma unroll
    for (int c4 = 0; c4 < 16; ++c4) {
        float4 v = sbo1_4[c4];
        o1[c4 * 4] = v.x; o1[c4 * 4 + 1] = v.y; o1[c4 * 4 + 2] = v.z; o1[c4 * 4 + 3] = v.w;
    }

    const float4* sWo1_4 = (const float4*)sWo1;
    const float4* hrow = (const float4*)(h + (size_t)i * 64);
    for (int k4 = 0; k4 < 16; ++k4) {
        float4 hv = hrow[k4];
        float hv_[4] = {hv.x, hv.y, hv.z, hv.w};
#pragma unroll
        for (int j = 0; j < 4; ++j) {
            float hk = hv_[j];
            int k = k4 * 4 + j;
#pragma unroll
            for (int c4 = 0; c4 < 16; ++c4) {
                float4 w = sWo1_4[k * 16 + c4];
                o1[c4 * 4]     = fmaf(hk, w.x, o1[c4 * 4]);
                o1[c4 * 4 + 1] = fmaf(hk, w.y, o1[c4 * 4 + 1]);
                o1[c4 * 4 + 2] = fmaf(hk, w.z, o1[c4 * 4 + 2]);
                o1[c4 * 4 + 3] = fmaf(hk, w.w, o1[c4 * 4 + 3]);
            }
        }
    }
    const float4* sWs2T_4 = (const float4*)sWs2T;
    for (int k = 0; k < 64; ++k) {
        float sek = sbs2[k];
#pragma unroll
        for (int j4 = 0; j4 < 8; ++j4) {
            float4 w = sWs2T_4[k * 8 + j4];
            sek = fmaf(hid[j4 * 4], w.x, fmaf(hid[j4 * 4 + 1], w.y,
                  fmaf(hid[j4 * 4 + 2], w.z, fmaf(hid[j4 * 4 + 3], w.w, sek))));
        }
#pragma unroll
        for (int c4 = 0; c4 < 16; ++c4) {
            float4 w = sWo1_4[(64 + k) * 16 + c4];
            o1[c4 * 4]     = fmaf(sek, w.x, o1[c4 * 4]);
            o1[c4 * 4 + 1] = fmaf(sek, w.y, o1[c4 * 4 + 1]);
            o1[c4 * 4 + 2] = fmaf(sek, w.z, o1[c4 * 4 + 2]);
            o1[c4 * 4 + 3] = fmaf(sek, w.w, o1[c4 * 4 + 3]);
        }
    }

    float o2[32];
    const float4* sbo2_4 = (const float4*)sbo2;
#pragma unroll
    for (int c4 = 0; c4 < 8; ++c4) {
        float4 v = sbo2_4[c4];
        o2[c4 * 4] = v.x; o2[c4 * 4 + 1] = v.y; o2[c4 * 4 + 2] = v.z; o2[c4 * 4 + 3] = v.w;
    }
    const float4* sWo2_4 = (const float4*)sWo2;
#pragma unroll
    for (int c = 0; c < 64; ++c) {
        float v = fmaxf(o1[c], 0.0f);
#pragma unroll
        for (int c4 = 0; c4 < 8; ++c4) {
            float4 w = sWo2_4[c * 8 + c4];
            o2[c4 * 4]     = fmaf(v, w.x, o2[c4 * 4]);
            o2[c4 * 4 + 1] = fmaf(v, w.y, o2[c4 * 4 + 1]);
            o2[c4 * 4 + 2] = fmaf(v, w.z, o2[c4 * 4 + 2]);
            o2[c4 * 4 + 3] = fmaf(v, w.w, o2[c4 * 4 + 3]);
        }
    }

    float o3 = bo3[0];
#pragma unroll
    for (int c2 = 0; c2 < 32; ++c2)
        o3 = fmaf(fmaxf(o2[c2], 0.0f), sWo3[c2], o3);

    out[i] = 1.0f / (1.0f + __expf(-o3));
}

// ==========================================================================
extern "C" void kernel_launch(void* const* d_in, const int* in_sizes, int n_in,
                              void* d_out, int out_size, void* d_ws, size_t ws_size,
                              hipStream_t stream) {
    const float* x     = (const float*)d_in[0];
    const int*   ei    = (const int*)d_in[1];
    const float* W_in  = (const float*)d_in[2];
    const float* b_in  = (const float*)d_in[3];
    const float* W_gcn = (const float*)d_in[4];
    const float* b_gcn = (const float*)d_in[5];
    const float* gamma = (const float*)d_in[6];
    const float* beta  = (const float*)d_in[7];
    const float* Ws1   = (const float*)d_in[8];
    const float* bs1   = (const float*)d_in[9];
    const float* Ws2   = (const float*)d_in[10];
    const float* bs2   = (const float*)d_in[11];
    const float* Wo1   = (const float*)d_in[12];
    const float* bo1   = (const float*)d_in[13];
    const float* Wo2   = (const float*)d_in[14];
    const float* bo2   = (const float*)d_in[15];
    const float* Wo3   = (const float*)d_in[16];
    const float* bo3   = (const float*)d_in[17];
    float* out = (float*)d_out;

    int n = in_sizes[0] / 128;
    int E = in_sizes[1] / 2;
    const int* row = ei;
    const int* col = ei + E;

    int npass8  = (n + NBU8 - 1) / NBU8;     // 2 @ n=100K
    int npass16 = (n + NB16 - 1) / NB16;     // 4 @ n=100K
    size_t NPU8  = (size_t)npass8 * NBU8;    // 131072
    size_t NPU16 = (size_t)npass16 * NB16;   // 131072

    auto al = [](size_t v) { return (v + 255) & ~(size_t)255; };
    size_t fixed = al((NPU8 + 256) * 4)          // roff
                 + al(NPU8 * 4)                  // cnt
                 + al(1024 * 4)                  // bsum
                 + 3 * al(NPU8 * 4)              // dis, odeg, infl
                 + al(NPU8 * 4)                  // odeg_i
                 + al(256)                       // maxima
                 + al((size_t)E * 4)             // esrc
                 + al((size_t)n * 64 * 4)        // h (f32)
                 + 2 * al((size_t)n * 64 * 2);   // hwsA, hwsB (f16)
    int NB = 256;                                // u8 kernels (hist/fill)
    auto partBytes = [&](int nb) {
        size_t a = (size_t)nb * NPU8;             // u8 partials
        size_t b2 = (size_t)(nb / 2) * NPU16 * 2; // u16 partials (NB/2 blocks)
        return a > b2 ? a : b2;
    };
    while (NB > 32 && fixed + partBytes(NB) > ws_size) NB >>= 1;
    int NBa = NB / 2;                            // histacc blocks
    int chunk  = (E + NB - 1) / NB;
    int chunkA = (E + NBa - 1) / NBa;

    char* p = (char*)d_ws;
    unsigned char*  part8  = (unsigned char*)p;     // [NB][NPU8] u8
    unsigned short* part16 = (unsigned short*)p;    // [NBa][NPU16] u16 (later phase)
    p += al(partBytes(NB));
    int* roff = (int*)p;        p += al((NPU8 + 256) * 4);
    int* cnt  = (int*)p;        p += al(NPU8 * 4);
    int* bsum = (int*)p;        p += al(1024 * 4);
    float* dis  = (float*)p;    p += al(NPU8 * 4);
    float* odeg = (float*)p;    p += al(NPU8 * 4);
    float* infl = (float*)p;    p += al(NPU8 * 4);
    int* odeg_i = (int*)p;      p += al(NPU8 * 4);
    unsigned* maxima = (unsigned*)p; p += al(256);
    int* esrc = (int*)p;        p += al((size_t)E * 4);
    float* h   = (float*)p;     p += al((size_t)n * 64 * 4);
    __half* hwsA = (__half*)p;  p += al((size_t)n * 64 * 2);
    __half* hwsB = (__half*)p;

    int gn = (n + 255) / 256;                // <=512 for scan2

    // ---- col-CSR build (no global atomics) ----
    kh_hist<<<dim3(NB, npass8), TPBH, 0, stream>>>(col, part8, maxima, E, chunk, (int)NPU8);
    k_scan1<<<gn, 256, 0, stream>>>(part8, NB, (int)NPU8, cnt, roff, bsum, n);
    k_scan2<<<1, 512, 0, stream>>>(bsum, gn);
    kh_prefix<<<gn, 256, 0, stream>>>(part8, NB, (int)NPU8, n, roff, bsum, cnt, dis, E);
    kh_fill<<<dim3(NB, npass8), TPBH, 0, stream>>>(col, row, roff, part8, esrc, E, chunk, (int)NPU8);

    // ---- structural stats ----
    kh_hist<<<dim3(NB, npass8), TPBH, 0, stream>>>(row, part8, maxima, E, chunk, (int)NPU8);
    kh_reduce_odeg<<<gn, 256, 0, stream>>>(part8, odeg, odeg_i, maxima, NB, (int)NPU8, n);
    kh_histacc<<<dim3(NBa, npass16), TPBH, 0, stream>>>(row, col, odeg_i, part16, E, chunkA, (int)NPU16);
    kh_reduce_infl<<<gn, 256, 0, stream>>>(part16, odeg, infl, maxima, NBa, (int)NPU16, n);

    // ---- GNN ----
    k_in_proj<<<(n + 63) / 64, 256, 0, stream>>>(x, W_in, b_in, W_gcn, dis, hwsA, n);

    int gg = (n + 31) / 32;
    k_gather<<<gg, 256, 0, stream>>>(roff, esrc, (const uint4*)hwsA, dis,
                                     b_gcn + 0 * 64, gamma + 0 * 64, beta + 0 * 64, h, n);
    k_gcn_mm<<<(n + 63) / 64, 256, 0, stream>>>(h, W_gcn + (size_t)1 * 64 * 64, dis,
                                                (unsigned*)hwsB, n);
    k_gather<<<gg, 256, 0, stream>>>(roff, esrc, (const uint4*)hwsB, dis,
                                     b_gcn + 1 * 64, gamma + 1 * 64, beta + 1 * 64, h, n);
    k_gcn_mm<<<(n + 63) / 64, 256, 0, stream>>>(h, W_gcn + (size_t)2 * 64 * 64, dis,
                                                (unsigned*)hwsA, n);
    k_gather<<<gg, 256, 0, stream>>>(roff, esrc, (const uint4*)hwsA, dis,
                                     b_gcn + 2 * 64, gamma + 2 * 64, beta + 2 * 64, h, n);

    k_final<<<gn, 256, 0, stream>>>(h, odeg, infl, maxima,
                                    Ws1, bs1, Ws2, bs2, Wo1, bo1, Wo2, bo2, Wo3, bo3,
                                    out, n);
}

// Round 10
// 831.959 us; speedup vs baseline: 1.2035x; 1.0383x over previous
//
#include <hip/hip_runtime.h>
#include <hip/hip_bf16.h>
#include <hip/hip_fp16.h>

#define NBU8 65536     // u8-packed bins per pass (64 KB LDS)
#define NB16 32768     // u16-packed bins per pass (64 KB LDS)
#define TPBH 1024

// ---- u8-packed LDS histogram; grid = (chunk_blocks, passes) --------------
// also zeroes maxima (runs before any reduce)
__global__ __launch_bounds__(TPBH) void kh_hist(const int* __restrict__ keys,
                                                unsigned char* __restrict__ part,
                                                unsigned* __restrict__ maxima,
                                                int E, int chunk, int npu) {
    __shared__ unsigned bins[NBU8 / 4];       // 64 KB, 4 u8 counters per word
    int b = blockIdx.x, t = threadIdx.x;
    if (b == 0 && blockIdx.y == 0 && t < 2) maxima[t] = 0u;
    int base = blockIdx.y * NBU8;
    int e0 = b * chunk, e1 = min(E, e0 + chunk);
    for (int j = t; j < NBU8 / 4; j += TPBH) bins[j] = 0u;
    __syncthreads();
    for (int e = e0 + t; e < e1; e += TPBH) {
        int k = keys[e] - base;
        if ((unsigned)k < NBU8) atomicAdd(&bins[k >> 2], 1u << ((k & 3) << 3));
    }
    __syncthreads();
    unsigned* dst = (unsigned*)(part + (size_t)b * npu + base);
    for (int j = t; j < NBU8 / 4; j += TPBH) dst[j] = bins[j];
}

// ---- scan stage 1 (fused u8-partial reduce): cnt + block-local ex-scan ---
__global__ __launch_bounds__(256) void k_scan1(const unsigned char* __restrict__ part,
                                               int nb, int npu,
                                               int* __restrict__ cnt,
                                               int* __restrict__ roff,
                                               int* __restrict__ bsum, int n) {
    __shared__ int s[256];
    int b = blockIdx.x, t = threadIdx.x;
    int i = b * 256 + t;
    int v = 0;
    if (i < n) {
        for (int k = 0; k < nb; ++k) v += part[(size_t)k * npu + i];
        cnt[i] = v;
    }
    s[t] = v;
    __syncthreads();
    for (int off = 1; off < 256; off <<= 1) {
        int x = (t >= off) ? s[t - off] : 0;
        __syncthreads();
        s[t] += x;
        __syncthreads();
    }
    if (i < n) roff[i] = s[t] - v;
    if (t == 255) bsum[b] = s[255];
}

// ---- scan stage 2: exclusive scan of block sums (1 block, nb<=512) -------
__global__ __launch_bounds__(512) void k_scan2(int* __restrict__ bsum, int nb) {
    __shared__ int s[512];
    int t = threadIdx.x;
    int v = (t < nb) ? bsum[t] : 0;
    s[t] = v;
    __syncthreads();
    for (int off = 1; off < 512; off <<= 1) {
        int x = (t >= off) ? s[t - off] : 0;
        __syncthreads();
        s[t] += x;
        __syncthreads();
    }
    if (t < nb) bsum[t] = s[t] - v;
}

// ---- prefix of u8 partials (XCD-grouped) + roff finalize + dis -----------
__global__ void kh_prefix(unsigned char* __restrict__ part, int nb, int npu, int n,
                          int* __restrict__ roff, const int* __restrict__ bsum,
                          const int* __restrict__ cnt, float* __restrict__ dis, int E) {
    int i = blockIdx.x * blockDim.x + threadIdx.x;
    if (i == 0) roff[n] = E;
    if (i >= n) return;
    roff[i] += bsum[i >> 8];
    dis[i] = rsqrtf((float)cnt[i] + 1.0f);       // +1 self loop
    int run = 0;
    for (int g = 0; g < 8; ++g) {
        for (int b = g; b < nb; b += 8) {
            size_t idx = (size_t)b * npu + i;
            int v = part[idx];
            part[idx] = (unsigned char)run;
            run += v;
        }
    }
}

// ---- CSR fill via u8-packed LDS cursors; grid = (chunk_blocks, passes) ---
__global__ __launch_bounds__(TPBH) void kh_fill(const int* __restrict__ col,
                                                const int* __restrict__ row,
                                                const int* __restrict__ roff,
                                                const unsigned char* __restrict__ pref,
                                                int* __restrict__ esrc,
                                                int E, int chunk, int npu) {
    __shared__ unsigned curs[NBU8 / 4];       // 64 KB, 4 u8 local counters/word
    int b = blockIdx.x, t = threadIdx.x;
    int base = blockIdx.y * NBU8;
    int e0 = b * chunk, e1 = min(E, e0 + chunk);
    for (int j = t; j < NBU8 / 4; j += TPBH) curs[j] = 0u;
    __syncthreads();
    const unsigned char* pb = pref + (size_t)b * npu;
    for (int e = e0 + t; e < e1; e += TPBH) {
        int c = col[e], r = row[e];
        int cl = c - base;
        if ((unsigned)cl < NBU8) {
            unsigned sh = (cl & 3) << 3;
            unsigned old = atomicAdd(&curs[cl >> 2], 1u << sh);
            unsigned local = (old >> sh) & 0xFFu;
            int slot = roff[c] + (int)pb[c] + (int)local;
            esrc[slot] = r;
        }
    }
}

// ---- u16 integer LDS histogram-accumulate: part[row] += odeg_i[col] ------
__global__ __launch_bounds__(TPBH) void kh_histacc(const int* __restrict__ row,
                                                   const int* __restrict__ col,
                                                   const int* __restrict__ odeg_i,
                                                   unsigned short* __restrict__ part,
                                                   int E, int chunk, int npu) {
    __shared__ unsigned bins[NB16 / 2];       // 64 KB, 2 u16 sums per word
    int b = blockIdx.x, t = threadIdx.x;
    int base = blockIdx.y * NB16;
    int e0 = b * chunk, e1 = min(E, e0 + chunk);
    for (int j = t; j < NB16 / 2; j += TPBH) bins[j] = 0u;
    __syncthreads();
    for (int e = e0 + t; e < e1; e += TPBH) {
        int r = row[e] - base;
        if ((unsigned)r < NB16)
            atomicAdd(&bins[r >> 1], (unsigned)odeg_i[col[e]] << ((r & 1) << 4));
    }
    __syncthreads();
    unsigned* dst = (unsigned*)(part + (size_t)b * npu + base);
    for (int j = t; j < NB16 / 2; j += TPBH) dst[j] = bins[j];
}

// ---- reduce u8 partials -> float odeg + int odeg + dmax ------------------
__global__ void kh_reduce_odeg(const unsigned char* __restrict__ part,
                               float* __restrict__ odeg, int* __restrict__ odeg_i,
                               unsigned* __restrict__ maxima, int nb, int npu, int n) {
    int i = blockIdx.x * blockDim.x + threadIdx.x;
    float od = 0.f;
    if (i < n) {
        int s = 0;
        for (int b = 0; b < nb; ++b) s += part[(size_t)b * npu + i];
        od = (float)s;
        odeg[i] = od;
        odeg_i[i] = s;
    }
    for (int off = 32; off > 0; off >>= 1) od = fmaxf(od, __shfl_down(od, off));
    if ((threadIdx.x & 63) == 0) atomicMax(&maxima[0], __float_as_uint(od));
}

// ---- reduce u16 partials -> infl + imax ----------------------------------
__global__ void kh_reduce_infl(const unsigned short* __restrict__ part,
                               const float* __restrict__ odeg,
                               float* __restrict__ infl, unsigned* __restrict__ maxima,
                               int nb, int npu, int n) {
    int i = blockIdx.x * blockDim.x + threadIdx.x;
    float fin = 0.f;
    if (i < n) {
        int s = 0;
        for (int b = 0; b < nb; ++b) s += part[(size_t)b * npu + i];
        float od = odeg[i];
        fin = (od > 0.f) ? (float)s / od : 0.f;
        infl[i] = fin;
    }
    for (int off = 32; off > 0; off >>= 1) fin = fmaxf(fin, __shfl_down(fin, off));
    if ((threadIdx.x & 63) == 0) atomicMax(&maxima[1], __float_as_uint(fin));
}

// ---- h0 = x@W_in+b_in, then hws0 = (h0@Wg0)*dis (fused) ------------------
// W/Wg0 read straight from global (wave-uniform broadcast rows -> L1);
// only the x-tile lives in LDS (16 KB) -> ~5 blocks/CU instead of 2.
__global__ __launch_bounds__(256) void k_in_proj(const float* __restrict__ x,
                                                 const float* __restrict__ W,
                                                 const float* __restrict__ b,
                                                 const float* __restrict__ Wg0,
                                                 const float* __restrict__ dis,
                                                 __half* __restrict__ hws, int n) {
    __shared__ alignas(16) float xs[64 * 64];    // 16 KB
    int t = threadIdx.x;
    int r0 = blockIdx.x * 64;
    int c = t & 63, rg = t >> 6;
    float acc[16];
    float bc = b[c];
#pragma unroll
    for (int i = 0; i < 16; ++i) acc[i] = bc;

    const float4* xs4 = (const float4*)xs;
    for (int half = 0; half < 2; ++half) {
        __syncthreads();
        for (int i = t; i < 64 * 16; i += 256) {
            int rr = i >> 4, k4 = i & 15;
            int r = r0 + rr;
            float4 v = (r < n) ? ((const float4*)x)[(size_t)r * 32 + half * 16 + k4]
                               : make_float4(0.f, 0.f, 0.f, 0.f);
            ((float4*)xs)[i] = v;
        }
        __syncthreads();
        for (int k4 = 0; k4 < 16; ++k4) {
            int kk = half * 64 + k4 * 4;
            float w0 = W[(kk + 0) * 64 + c];
            float w1 = W[(kk + 1) * 64 + c];
            float w2 = W[(kk + 2) * 64 + c];
            float w3 = W[(kk + 3) * 64 + c];
#pragma unroll
            for (int i = 0; i < 16; ++i) {
                float4 xv = xs4[(rg * 16 + i) * 16 + k4];
                acc[i] = fmaf(xv.x, w0, fmaf(xv.y, w1, fmaf(xv.z, w2, fmaf(xv.w, w3, acc[i]))));
            }
        }
    }
    // stage h tile into xs, then fused 64x64 mm (k4-outer) + dis scale -> fp16
    __syncthreads();
#pragma unroll
    for (int i = 0; i < 16; ++i) xs[(rg * 16 + i) * 64 + c] = acc[i];
    __syncthreads();
    float s[16];
#pragma unroll
    for (int i = 0; i < 16; ++i) s[i] = 0.f;
    for (int k4 = 0; k4 < 16; ++k4) {
        float w0 = Wg0[(k4 * 4 + 0) * 64 + c];
        float w1 = Wg0[(k4 * 4 + 1) * 64 + c];
        float w2 = Wg0[(k4 * 4 + 2) * 64 + c];
        float w3 = Wg0[(k4 * 4 + 3) * 64 + c];
#pragma unroll
        for (int i = 0; i < 16; ++i) {
            float4 hv = xs4[(rg * 16 + i) * 16 + k4];
            s[i] = fmaf(hv.x, w0, fmaf(hv.y, w1, fmaf(hv.z, w2, fmaf(hv.w, w3, s[i]))));
        }
    }
#pragma unroll
    for (int i = 0; i < 16; ++i) {
        int r = r0 + rg * 16 + i;
        if (r < n) hws[(size_t)r * 64 + c] = __float2half(s[i] * dis[r]);
    }
}

// -------- hw = h @ W_gcn; hws(half2) = hw * dis[r]; W via global ----------
__global__ __launch_bounds__(256) void k_gcn_mm(const float* __restrict__ h,
                                                const float* __restrict__ Wg,
                                                const float* __restrict__ dis,
                                                unsigned* __restrict__ hws, int n) {
    __shared__ alignas(16) float xs[64 * 64];    // 16 KB
    int t = threadIdx.x;
    int r0 = blockIdx.x * 64;
    for (int i = t; i < 64 * 16; i += 256) {
        int rr = i >> 4, k4 = i & 15;
        int r = r0 + rr;
        float4 v = (r < n) ? ((const float4*)h)[(size_t)r * 16 + k4]
                           : make_float4(0.f, 0.f, 0.f, 0.f);
        ((float4*)xs)[i] = v;
    }
    __syncthreads();
    int cl = t & 31, rg = t >> 5;            // 2 features x (8 row-groups x 8 rows)
    const float4* xs4 = (const float4*)xs;
    const float2* Wg2 = (const float2*)Wg;
    float a0[8], a1[8];
#pragma unroll
    for (int i = 0; i < 8; ++i) { a0[i] = 0.f; a1[i] = 0.f; }
    for (int k4 = 0; k4 < 16; ++k4) {
        float2 w0 = Wg2[(k4 * 4 + 0) * 32 + cl];
        float2 w1 = Wg2[(k4 * 4 + 1) * 32 + cl];
        float2 w2 = Wg2[(k4 * 4 + 2) * 32 + cl];
        float2 w3 = Wg2[(k4 * 4 + 3) * 32 + cl];
#pragma unroll
        for (int i = 0; i < 8; ++i) {
            float4 xv = xs4[(rg * 8 + i) * 16 + k4];
            a0[i] = fmaf(xv.x, w0.x, fmaf(xv.y, w1.x, fmaf(xv.z, w2.x, fmaf(xv.w, w3.x, a0[i]))));
            a1[i] = fmaf(xv.x, w0.y, fmaf(xv.y, w1.y, fmaf(xv.z, w2.y, fmaf(xv.w, w3.y, a1[i]))));
        }
    }
#pragma unroll
    for (int i = 0; i < 8; ++i) {
        int r = r0 + rg * 8 + i;
        if (r < n) {
            float d = dis[r];
            __half2 hv = __floats2half2_rn(a0[i] * d, a1[i] * d);
            hws[(size_t)r * 32 + cl] = *(unsigned*)&hv;
        }
    }
}

// -------- gather + BN/bias/ReLU: 8 lanes/node, uint4 (8 feats) per lane ---
__global__ __launch_bounds__(256) void k_gather(const int* __restrict__ roff,
                                                const int* __restrict__ esrc,
                                                const uint4* __restrict__ hws,
                                                const float* __restrict__ dis,
                                                const float* __restrict__ bg,
                                                const float* __restrict__ gamma,
                                                const float* __restrict__ beta,
                                                float* __restrict__ h, int n) {
    int t = threadIdx.x;
    int node = blockIdx.x * 32 + (t >> 3);
    int ln = t & 7;                           // uint4 index within row (8 feats)
    if (node >= n) return;

    int beg = roff[node], end = roff[node + 1];
    float a[8];
#pragma unroll
    for (int j = 0; j < 8; ++j) a[j] = 0.f;
    union { unsigned u; __half2 h2; } cv;
#define ACC(v) { cv.u = (v).x; float2 f_ = __half22float2(cv.h2); a[0] += f_.x; a[1] += f_.y; \
                 cv.u = (v).y; f_ = __half22float2(cv.h2);        a[2] += f_.x; a[3] += f_.y; \
                 cv.u = (v).z; f_ = __half22float2(cv.h2);        a[4] += f_.x; a[5] += f_.y; \
                 cv.u = (v).w; f_ = __half22float2(cv.h2);        a[6] += f_.x; a[7] += f_.y; }
    {
        uint4 v = hws[(size_t)node * 8 + ln];   // self-loop term
        ACC(v)
    }
    int e = beg;
    for (; e + 4 <= end; e += 4) {
        int r0 = esrc[e], r1 = esrc[e + 1], r2 = esrc[e + 2], r3 = esrc[e + 3];
        uint4 v0 = hws[(size_t)r0 * 8 + ln];
        uint4 v1 = hws[(size_t)r1 * 8 + ln];
        uint4 v2 = hws[(size_t)r2 * 8 + ln];
        uint4 v3 = hws[(size_t)r3 * 8 + ln];
        ACC(v0) ACC(v1) ACC(v2) ACC(v3)
    }
    for (; e < end; ++e) {
        uint4 v = hws[(size_t)esrc[e] * 8 + ln];
        ACC(v)
    }
#undef ACC
    float d = dis[node];
    float inv = rsqrtf(1.0f + 1e-5f);
    float4 g0 = ((const float4*)gamma)[ln * 2], g1 = ((const float4*)gamma)[ln * 2 + 1];
    float4 b0 = ((const float4*)beta)[ln * 2],  b1 = ((const float4*)beta)[ln * 2 + 1];
    float4 q0 = ((const float4*)bg)[ln * 2],    q1 = ((const float4*)bg)[ln * 2 + 1];
    float4 o0, o1;
    o0.x = fmaxf(fmaf(a[0] * d + q0.x, g0.x * inv, b0.x), 0.0f);
    o0.y = fmaxf(fmaf(a[1] * d + q0.y, g0.y * inv, b0.y), 0.0f);
    o0.z = fmaxf(fmaf(a[2] * d + q0.z, g0.z * inv, b0.z), 0.0f);
    o0.w = fmaxf(fmaf(a[3] * d + q0.w, g0.w * inv, b0.w), 0.0f);
    o1.x = fmaxf(fmaf(a[4] * d + q1.x, g1.x * inv, b1.x), 0.0f);
    o1.y = fmaxf(fmaf(a[5] * d + q1.y, g1.y * inv, b1.y), 0.0f);
    o1.z = fmaxf(fmaf(a[6] * d + q1.z, g1.z * inv, b1.z), 0.0f);
    o1.w = fmaxf(fmaf(a[7] * d + q1.w, g1.w * inv, b1.w), 0.0f);
    ((float4*)h)[(size_t)node * 16 + ln * 2]     = o0;
    ((float4*)h)[(size_t)node * 16 + ln * 2 + 1] = o1;
}

// -------- fused structural MLP + output head (one node per thread) --------
__global__ __launch_bounds__(256) void k_final(const float* __restrict__ h,
                                               const float* __restrict__ odeg,
                                               const float* __restrict__ infl,
                                               const unsigned* __restrict__ maxima,
                                               const float* __restrict__ Ws1, const float* __restrict__ bs1,
                                               const float* __restrict__ Ws2, const float* __restrict__ bs2,
                                               const float* __restrict__ Wo1, const float* __restrict__ bo1,
                                               const float* __restrict__ Wo2, const float* __restrict__ bo2,
                                               const float* __restrict__ Wo3, const float* __restrict__ bo3,
                                               float* __restrict__ out, int n) {
    __shared__ alignas(16) float sWs1[96], sbs1[32], sWs2T[64 * 32], sbs2[64];
    __shared__ alignas(16) float sWo1[128 * 64], sbo1[64], sWo2[64 * 32], sbo2[32], sWo3[32];
    int t = threadIdx.x;
    for (int i = t; i < 96; i += 256) sWs1[i] = Ws1[i];
    for (int i = t; i < 2048; i += 256) {            // transpose W_s2: [32][64] -> [64][32]
        int j = i >> 6, k = i & 63;
        sWs2T[k * 32 + j] = Ws2[i];
    }
    for (int i = t; i < 8192; i += 256) sWo1[i] = Wo1[i];
    for (int i = t; i < 2048; i += 256) sWo2[i] = Wo2[i];
    if (t < 32) { sbs1[t] = bs1[t]; sbo2[t] = bo2[t]; sWo3[t] = Wo3[t]; }
    if (t < 64) { sbs2[t] = bs2[t]; sbo1[t] = bo1[t]; }
    __syncthreads();

    int i = blockIdx.x * 256 + t;
    if (i >= n) return;

    float dmax = __uint_as_float(maxima[0]);
    float imax = __uint_as_float(maxima[1]);
    float od = odeg[i];
    float sf0 = (dmax > 0.0f) ? od / dmax : od;
    float fin = infl[i];
    float sf2 = (imax > 0.0f) ? fin / imax : fin;

    float hid[32];
#pragma unroll
    for (int j = 0; j < 32; ++j)
        hid[j] = fmaxf(fmaf(sf0, sWs1[j], fmaf(sf2, sWs1[64 + j], sbs1[j])), 0.0f);

    float o1[64];
    const float4* sbo1_4 = (const float4*)sbo1;
#pragma unroll
    for (int c4 = 0; c4 < 16; ++c4) {
        float4 v = sbo1_4[c4];
        o1[c4 * 4] = v.x; o1[c4 * 4 + 1] = v.y; o1[c4 * 4 + 2] = v.z; o1[c4 * 4 + 3] = v.w;
    }

    const float4* sWo1_4 = (const float4*)sWo1;
    const float4* hrow = (const float4*)(h + (size_t)i * 64);
    for (int k4 = 0; k4 < 16; ++k4) {
        float4 hv = hrow[k4];
        float hv_[4] = {hv.x, hv.y, hv.z, hv.w};
#pragma unroll
        for (int j = 0; j < 4; ++j) {
            float hk = hv_[j];
            int k = k4 * 4 + j;
#pragma unroll
            for (int c4 = 0; c4 < 16; ++c4) {
                float4 w = sWo1_4[k * 16 + c4];
                o1[c4 * 4]     = fmaf(hk, w.x, o1[c4 * 4]);
                o1[c4 * 4 + 1] = fmaf(hk, w.y, o1[c4 * 4 + 1]);
                o1[c4 * 4 + 2] = fmaf(hk, w.z, o1[c4 * 4 + 2]);
                o1[c4 * 4 + 3] = fmaf(hk, w.w, o1[c4 * 4 + 3]);
            }
        }
    }
    const float4* sWs2T_4 = (const float4*)sWs2T;
    for (int k = 0; k < 64; ++k) {
        float sek = sbs2[k];
#pragma unroll
        for (int j4 = 0; j4 < 8; ++j4) {
            float4 w = sWs2T_4[k * 8 + j4];
            sek = fmaf(hid[j4 * 4], w.x, fmaf(hid[j4 * 4 + 1], w.y,
                  fmaf(hid[j4 * 4 + 2], w.z, fmaf(hid[j4 * 4 + 3], w.w, sek))));
        }
#pragma unroll
        for (int c4 = 0; c4 < 16; ++c4) {
            float4 w = sWo1_4[(64 + k) * 16 + c4];
            o1[c4 * 4]     = fmaf(sek, w.x, o1[c4 * 4]);
            o1[c4 * 4 + 1] = fmaf(sek, w.y, o1[c4 * 4 + 1]);
            o1[c4 * 4 + 2] = fmaf(sek, w.z, o1[c4 * 4 + 2]);
            o1[c4 * 4 + 3] = fmaf(sek, w.w, o1[c4 * 4 + 3]);
        }
    }

    float o2[32];
    const float4* sbo2_4 = (const float4*)sbo2;
#pragma unroll
    for (int c4 = 0; c4 < 8; ++c4) {
        float4 v = sbo2_4[c4];
        o2[c4 * 4] = v.x; o2[c4 * 4 + 1] = v.y; o2[c4 * 4 + 2] = v.z; o2[c4 * 4 + 3] = v.w;
    }
    const float4* sWo2_4 = (const float4*)sWo2;
#pragma unroll
    for (int c = 0; c < 64; ++c) {
        float v = fmaxf(o1[c], 0.0f);
#pragma unroll
        for (int c4 = 0; c4 < 8; ++c4) {
            float4 w = sWo2_4[c * 8 + c4];
            o2[c4 * 4]     = fmaf(v, w.x, o2[c4 * 4]);
            o2[c4 * 4 + 1] = fmaf(v, w.y, o2[c4 * 4 + 1]);
            o2[c4 * 4 + 2] = fmaf(v, w.z, o2[c4 * 4 + 2]);
            o2[c4 * 4 + 3] = fmaf(v, w.w, o2[c4 * 4 + 3]);
        }
    }

    float o3 = bo3[0];
#pragma unroll
    for (int c2 = 0; c2 < 32; ++c2)
        o3 = fmaf(fmaxf(o2[c2], 0.0f), sWo3[c2], o3);

    out[i] = 1.0f / (1.0f + __expf(-o3));
}

// ==========================================================================
extern "C" void kernel_launch(void* const* d_in, const int* in_sizes, int n_in,
                              void* d_out, int out_size, void* d_ws, size_t ws_size,
                              hipStream_t stream) {
    const float* x     = (const float*)d_in[0];
    const int*   ei    = (const int*)d_in[1];
    const float* W_in  = (const float*)d_in[2];
    const float* b_in  = (const float*)d_in[3];
    const float* W_gcn = (const float*)d_in[4];
    const float* b_gcn = (const float*)d_in[5];
    const float* gamma = (const float*)d_in[6];
    const float* beta  = (const float*)d_in[7];
    const float* Ws1   = (const float*)d_in[8];
    const float* bs1   = (const float*)d_in[9];
    const float* Ws2   = (const float*)d_in[10];
    const float* bs2   = (const float*)d_in[11];
    const float* Wo1   = (const float*)d_in[12];
    const float* bo1   = (const float*)d_in[13];
    const float* Wo2   = (const float*)d_in[14];
    const float* bo2   = (const float*)d_in[15];
    const float* Wo3   = (const float*)d_in[16];
    const float* bo3   = (const float*)d_in[17];
    float* out = (float*)d_out;

    int n = in_sizes[0] / 128;
    int E = in_sizes[1] / 2;
    const int* row = ei;
    const int* col = ei + E;

    int npass8  = (n + NBU8 - 1) / NBU8;     // 2 @ n=100K
    int npass16 = (n + NB16 - 1) / NB16;     // 4 @ n=100K
    size_t NPU8  = (size_t)npass8 * NBU8;    // 131072
    size_t NPU16 = (size_t)npass16 * NB16;   // 131072

    auto al = [](size_t v) { return (v + 255) & ~(size_t)255; };
    size_t fixed = al((NPU8 + 256) * 4)          // roff
                 + al(NPU8 * 4)                  // cnt
                 + al(1024 * 4)                  // bsum
                 + 3 * al(NPU8 * 4)              // dis, odeg, infl
                 + al(NPU8 * 4)                  // odeg_i
                 + al(256)                       // maxima
                 + al((size_t)E * 4)             // esrc
                 + al((size_t)n * 64 * 4)        // h (f32)
                 + 2 * al((size_t)n * 64 * 2);   // hwsA, hwsB (f16)
    int NB = 256;                                // u8 kernels (hist/fill)
    auto partBytes = [&](int nb) {
        size_t a = (size_t)nb * NPU8;             // u8 partials
        size_t b2 = (size_t)(nb / 2) * NPU16 * 2; // u16 partials (NB/2 blocks)
        return a > b2 ? a : b2;
    };
    while (NB > 32 && fixed + partBytes(NB) > ws_size) NB >>= 1;
    int NBa = NB / 2;                            // histacc blocks
    int chunk  = (E + NB - 1) / NB;
    int chunkA = (E + NBa - 1) / NBa;

    char* p = (char*)d_ws;
    unsigned char*  part8  = (unsigned char*)p;     // [NB][NPU8] u8
    unsigned short* part16 = (unsigned short*)p;    // [NBa][NPU16] u16 (later phase)
    p += al(partBytes(NB));
    int* roff = (int*)p;        p += al((NPU8 + 256) * 4);
    int* cnt  = (int*)p;        p += al(NPU8 * 4);
    int* bsum = (int*)p;        p += al(1024 * 4);
    float* dis  = (float*)p;    p += al(NPU8 * 4);
    float* odeg = (float*)p;    p += al(NPU8 * 4);
    float* infl = (float*)p;    p += al(NPU8 * 4);
    int* odeg_i = (int*)p;      p += al(NPU8 * 4);
    unsigned* maxima = (unsigned*)p; p += al(256);
    int* esrc = (int*)p;        p += al((size_t)E * 4);
    float* h   = (float*)p;     p += al((size_t)n * 64 * 4);
    __half* hwsA = (__half*)p;  p += al((size_t)n * 64 * 2);
    __half* hwsB = (__half*)p;

    int gn = (n + 255) / 256;                // <=512 for scan2

    // ---- col-CSR build (no global atomics) ----
    kh_hist<<<dim3(NB, npass8), TPBH, 0, stream>>>(col, part8, maxima, E, chunk, (int)NPU8);
    k_scan1<<<gn, 256, 0, stream>>>(part8, NB, (int)NPU8, cnt, roff, bsum, n);
    k_scan2<<<1, 512, 0, stream>>>(bsum, gn);
    kh_prefix<<<gn, 256, 0, stream>>>(part8, NB, (int)NPU8, n, roff, bsum, cnt, dis, E);
    kh_fill<<<dim3(NB, npass8), TPBH, 0, stream>>>(col, row, roff, part8, esrc, E, chunk, (int)NPU8);

    // ---- structural stats ----
    kh_hist<<<dim3(NB, npass8), TPBH, 0, stream>>>(row, part8, maxima, E, chunk, (int)NPU8);
    kh_reduce_odeg<<<gn, 256, 0, stream>>>(part8, odeg, odeg_i, maxima, NB, (int)NPU8, n);
    kh_histacc<<<dim3(NBa, npass16), TPBH, 0, stream>>>(row, col, odeg_i, part16, E, chunkA, (int)NPU16);
    kh_reduce_infl<<<gn, 256, 0, stream>>>(part16, odeg, infl, maxima, NBa, (int)NPU16, n);

    // ---- GNN ----
    k_in_proj<<<(n + 63) / 64, 256, 0, stream>>>(x, W_in, b_in, W_gcn, dis, hwsA, n);

    int gg = (n + 31) / 32;
    k_gather<<<gg, 256, 0, stream>>>(roff, esrc, (const uint4*)hwsA, dis,
                                     b_gcn + 0 * 64, gamma + 0 * 64, beta + 0 * 64, h, n);
    k_gcn_mm<<<(n + 63) / 64, 256, 0, stream>>>(h, W_gcn + (size_t)1 * 64 * 64, dis,
                                                (unsigned*)hwsB, n);
    k_gather<<<gg, 256, 0, stream>>>(roff, esrc, (const uint4*)hwsB, dis,
                                     b_gcn + 1 * 64, gamma + 1 * 64, beta + 1 * 64, h, n);
    k_gcn_mm<<<(n + 63) / 64, 256, 0, stream>>>(h, W_gcn + (size_t)2 * 64 * 64, dis,
                                                (unsigned*)hwsA, n);
    k_gather<<<gg, 256, 0, stream>>>(roff, esrc, (const uint4*)hwsA, dis,
                                     b_gcn + 2 * 64, gamma + 2 * 64, beta + 2 * 64, h, n);

    k_final<<<gn, 256, 0, stream>>>(h, odeg, infl, maxima,
                                    Ws1, bs1, Ws2, bs2, Wo1, bo1, Wo2, bo2, Wo3, bo3,
                                    out, n);
}